// Round 1
// baseline (480.384 us; speedup 1.0000x reference)
//
#include <hip/hip_runtime.h>
#include <hip/hip_bf16.h>

typedef __bf16 bf16x8 __attribute__((ext_vector_type(8)));
typedef float  floatx4 __attribute__((ext_vector_type(4)));

constexpr int B_SZ  = 1024;
constexpr int NB    = 1024;
constexpr int DIN   = 64;
constexpr int DOUT  = 64;
constexpr int M_TILE = 128;               // batch rows per workgroup
constexpr int LDS_STRIDE = 72;            // bf16 elems per W row (pad 64 -> 72, keeps 16B align)

__global__ __launch_bounds__(256)
void block_linear_kernel(const float* __restrict__ x,
                         const float* __restrict__ W,
                         const float* __restrict__ bias,
                         float* __restrict__ out)
{
    __shared__ __bf16 sW[DOUT * LDS_STRIDE];   // 9216 B

    const int bid  = blockIdx.x;
    const int n    = bid >> 3;          // block index (shares W[n] across 8 m-tiles)
    const int mt   = bid & 7;           // which 128-row m-tile
    const int tid  = threadIdx.x;
    const int wave = tid >> 6;
    const int lane = tid & 63;
    const int r    = lane & 15;         // row-in-tile for A, col for B/D
    const int q    = lane >> 4;         // quad

    // ---- stage W[n] (64x64 fp32, 16 KB) -> LDS bf16, coalesced float4 loads ----
    {
        const float4* Wf4 = reinterpret_cast<const float4*>(W + (size_t)n * DOUT * DIN);
        #pragma unroll
        for (int i = 0; i < 4; ++i) {
            const int e  = i * 256 + tid;       // float4 index in 64x64 tile (1024 total)
            const float4 f = Wf4[e];
            const int o  = e >> 4;              // (e*4)/64
            const int k0 = (e & 15) << 2;       // (e*4)%64
            union { __bf16 h[4]; ushort4 u; } pk;
            pk.h[0] = (__bf16)f.x; pk.h[1] = (__bf16)f.y;
            pk.h[2] = (__bf16)f.z; pk.h[3] = (__bf16)f.w;
            *reinterpret_cast<ushort4*>(&sW[o * LDS_STRIDE + k0]) = pk.u;
        }
    }

    // ---- A fragments: per-lane direct global loads (rows are 256B contiguous) ----
    // A[m = lane&15][k = quad*8 + j]  (verified m120 layout)
    const int m0 = mt * M_TILE + wave * 32;     // this wave's base batch row
    bf16x8 afrag[2][2];
    #pragma unroll
    for (int mtile = 0; mtile < 2; ++mtile) {
        #pragma unroll
        for (int ks = 0; ks < 2; ++ks) {
            const float* p = x + ((size_t)(m0 + mtile * 16 + r) * NB + n) * DIN
                               + ks * 32 + q * 8;
            const float4 f0 = *reinterpret_cast<const float4*>(p);
            const float4 f1 = *reinterpret_cast<const float4*>(p + 4);
            bf16x8 a;
            a[0] = (__bf16)f0.x; a[1] = (__bf16)f0.y; a[2] = (__bf16)f0.z; a[3] = (__bf16)f0.w;
            a[4] = (__bf16)f1.x; a[5] = (__bf16)f1.y; a[6] = (__bf16)f1.z; a[7] = (__bf16)f1.w;
            afrag[mtile][ks] = a;
        }
    }

    __syncthreads();

    // ---- B fragments from LDS: B[n = lane&15][k = quad*8 + j] = W[o][k] ----
    bf16x8 bfrag[4][2];
    #pragma unroll
    for (int ot = 0; ot < 4; ++ot) {
        #pragma unroll
        for (int ks = 0; ks < 2; ++ks) {
            const int o = ot * 16 + r;
            bfrag[ot][ks] = *reinterpret_cast<const bf16x8*>(
                &sW[o * LDS_STRIDE + ks * 32 + q * 8]);
        }
    }

    // ---- MFMA: 2 m-subtiles x 4 o-tiles x 2 K-steps = 16 mfma ----
    floatx4 acc[2][4];
    #pragma unroll
    for (int mtile = 0; mtile < 2; ++mtile)
        #pragma unroll
        for (int ot = 0; ot < 4; ++ot)
            acc[mtile][ot] = (floatx4){0.f, 0.f, 0.f, 0.f};

    #pragma unroll
    for (int mtile = 0; mtile < 2; ++mtile) {
        #pragma unroll
        for (int ot = 0; ot < 4; ++ot) {
            #pragma unroll
            for (int ks = 0; ks < 2; ++ks) {
                acc[mtile][ot] = __builtin_amdgcn_mfma_f32_16x16x32_bf16(
                    afrag[mtile][ks], bfrag[ot][ks], acc[mtile][ot], 0, 0, 0);
            }
        }
    }

    // ---- epilogue: + bias, store. D: col = lane&15, row = quad*4 + reg ----
    #pragma unroll
    for (int ot = 0; ot < 4; ++ot) {
        const float bv = bias[n * DOUT + ot * 16 + r];
        #pragma unroll
        for (int mtile = 0; mtile < 2; ++mtile) {
            #pragma unroll
            for (int reg = 0; reg < 4; ++reg) {
                const int row = m0 + mtile * 16 + q * 4 + reg;
                out[((size_t)row * NB + n) * DOUT + ot * 16 + r]
                    = acc[mtile][ot][reg] + bv;
            }
        }
    }
}

extern "C" void kernel_launch(void* const* d_in, const int* in_sizes, int n_in,
                              void* d_out, int out_size, void* d_ws, size_t ws_size,
                              hipStream_t stream) {
    const float* x  = (const float*)d_in[0];
    const float* W  = (const float*)d_in[1];
    const float* b  = (const float*)d_in[2];
    float* out      = (float*)d_out;

    dim3 grid(NB * (B_SZ / M_TILE));   // 8192
    dim3 block(256);
    hipLaunchKernelGGL(block_linear_kernel, grid, block, 0, stream, x, W, b, out);
}